// Round 3
// baseline (774.248 us; speedup 1.0000x reference)
//
#include <hip/hip_runtime.h>
#include <hip/hip_bf16.h>

// Problem constants
#define T_ 4096
#define H_ 1024
#define E_ 16
#define I_ 768
#define KTOP 8
#define MAXSLOT 4096      // per-expert token list capacity (hard upper bound)
#define ACT_ROWS 34816    // >= 32768 + 16*127 (per-expert pad to 128)

typedef __attribute__((ext_vector_type(8))) short bf16x8;
typedef __attribute__((ext_vector_type(4))) float f32x4;

__device__ __forceinline__ unsigned short f2bf(float f) {
  unsigned u = __builtin_bit_cast(unsigned, f);
  u += 0x7fff + ((u >> 16) & 1);   // round-to-nearest-even
  return (unsigned short)(u >> 16);
}

typedef __attribute__((address_space(3))) void lds_void;
typedef __attribute__((address_space(1))) void g_void;

__device__ __forceinline__ void gload_lds16(const void* g, void* l) {
  __builtin_amdgcn_global_load_lds((g_void*)g, (lds_void*)l, 16, 0, 0);
}

// ---------------- Router: logits -> softmax -> top8 -> append to lists ------
// one wave per token; e = lane&15, chunk = lane>>4 (4 H-chunks of 256)
__global__ void router_kernel(const float* __restrict__ x,
                              const float* __restrict__ gate_w,
                              int* __restrict__ cnt,
                              int* __restrict__ tok_list,
                              float* __restrict__ rw_list) {
  int t = blockIdx.x;
  int lane = threadIdx.x;
  int e = lane & 15;
  int chunk = lane >> 4;
  const float* xr = x + (size_t)t * H_;
  int h0 = chunk * 256;
  float partial = 0.f;
  for (int i = 0; i < 256; i += 4) {
    float4 xv = *reinterpret_cast<const float4*>(xr + h0 + i);
    partial += xv.x * gate_w[(size_t)(h0 + i    ) * E_ + e];
    partial += xv.y * gate_w[(size_t)(h0 + i + 1) * E_ + e];
    partial += xv.z * gate_w[(size_t)(h0 + i + 2) * E_ + e];
    partial += xv.w * gate_w[(size_t)(h0 + i + 3) * E_ + e];
  }
  partial += __shfl_xor(partial, 16);
  partial += __shfl_xor(partial, 32);
  float logit = partial;
  float m = logit;
  for (int d = 1; d < 16; d <<= 1) m = fmaxf(m, __shfl_xor(m, d));
  float p = __expf(logit - m);
  int base = lane & ~15;
  int rank = 0;
  for (int j = 0; j < 16; ++j) {
    float pj = __shfl(p, base + j);
    rank += (pj > p) || (pj == p && j < e);
  }
  bool sel = rank < KTOP;
  float contrib = sel ? p : 0.f;
  float s = contrib;
  for (int d = 1; d < 16; d <<= 1) s += __shfl_xor(s, d);
  float w = sel ? p / s : 0.f;
  if (lane < 16 && sel) {
    int slot = atomicAdd(&cnt[e], 1);
    tok_list[e * MAXSLOT + slot] = t;
    rw_list[e * MAXSLOT + slot] = w;
  }
}

// ---------------- Offsets: per-expert padded prefix sum (1 thread) ----------
__global__ void offsets_kernel(const int* __restrict__ cnt,
                               int* __restrict__ off,
                               int* __restrict__ ntiles) {
  int acc = 0;
  for (int e = 0; e < E_; ++e) {
    off[e] = acc;
    int nt = (cnt[e] + 127) >> 7;
    ntiles[e] = nt;
    acc += nt << 7;
  }
}

// ---------------- Cast x (f32 -> bf16), 4 elems/thread ----------------
__global__ void cast_x_kernel(const float* __restrict__ x,
                              unsigned short* __restrict__ xb) {
  int idx = blockIdx.x * blockDim.x + threadIdx.x;
  float4 v = reinterpret_cast<const float4*>(x)[idx];
  ushort4 o;
  o.x = f2bf(v.x); o.y = f2bf(v.y); o.z = f2bf(v.z); o.w = f2bf(v.w);
  *reinterpret_cast<ushort4*>(xb + (size_t)idx * 4) = o;
}

// ---------------- Transpose+cast w1/w3: [E][H][I] f32 -> [E][I][H] bf16 -----
__global__ void transpose_w13_kernel(const float* __restrict__ w1,
                                     const float* __restrict__ w3,
                                     unsigned short* __restrict__ w1t,
                                     unsigned short* __restrict__ w3t) {
  __shared__ float tile[64][65];
  int i0 = blockIdx.x * 64;
  int h0 = blockIdx.y * 64;
  int e = blockIdx.z & 15;
  const float* src = (blockIdx.z < 16 ? w1 : w3) + (size_t)e * H_ * I_;
  unsigned short* dst = (blockIdx.z < 16 ? w1t : w3t) + (size_t)e * I_ * H_;
  int tx = threadIdx.x & 63, ty = threadIdx.x >> 6;
  for (int r = 0; r < 64; r += 4)
    tile[ty + r][tx] = src[(size_t)(h0 + ty + r) * I_ + i0 + tx];
  __syncthreads();
  for (int r = 0; r < 64; r += 4) {
    int i = ty + r;
    dst[(size_t)(i0 + i) * H_ + h0 + tx] = f2bf(tile[tx][i]);
  }
}

// ---------------- Transpose+cast w2: [E][I][H] f32 -> [E][H][I] bf16 --------
__global__ void transpose_w2_kernel(const float* __restrict__ w2,
                                    unsigned short* __restrict__ w2te) {
  __shared__ float tile[64][65];
  int h0 = blockIdx.x * 64;
  int i0 = blockIdx.y * 64;
  int e = blockIdx.z;
  const float* src = w2 + (size_t)e * I_ * H_;
  int tx = threadIdx.x & 63, ty = threadIdx.x >> 6;
  for (int r = 0; r < 64; r += 4)
    tile[ty + r][tx] = src[(size_t)(i0 + ty + r) * H_ + h0 + tx];
  __syncthreads();
  for (int r = 0; r < 64; r += 4) {
    int h = ty + r;
    w2te[((size_t)e * H_ + h0 + h) * I_ + i0 + tx] = f2bf(tile[tx][h]);
  }
}

// ---------------- Gathered up/gate GEMM + SwiGLU + route-scale --------------
// Per expert e, row-tile = 128 gathered token slots; 128x64 tile, BK=32,
// 4 waves: w0,w1 stage A (gathered); w2 stages B1; w3 stages B3.
__global__ __launch_bounds__(256) void moe_up_kernel(
    const unsigned short* __restrict__ xb,    // [T][H] bf16
    const unsigned short* __restrict__ w1t,   // [E][I][H] bf16
    const unsigned short* __restrict__ w3t,   // [E][I][H] bf16
    const int* __restrict__ tok_list,         // [E][MAXSLOT]
    const float* __restrict__ rw_list,        // [E][MAXSLOT]
    const int* __restrict__ off,              // [E]
    const int* __restrict__ ntiles,           // [E]
    unsigned short* __restrict__ act_g) {     // [ACT_ROWS][I] bf16
  const int e = blockIdx.z;
  const int tile = blockIdx.x;
  if (tile >= ntiles[e]) return;

  __shared__ __align__(16) unsigned short Asm[128 * 32];   // 8KB
  __shared__ __align__(16) unsigned short B1sm[64 * 32];   // 4KB
  __shared__ __align__(16) unsigned short B3sm[64 * 32];   // 4KB
  __shared__ int tok_sm[128];
  __shared__ float rw_sm[128];

  const int col0 = blockIdx.y * 64;
  const int tid = threadIdx.x;
  const int lane = tid & 63;
  const int w = tid >> 6;
  const int wm = w >> 1, wn = w & 1;
  const int slot0 = off[e] + tile * 128;

  if (tid < 128) {
    int li = e * MAXSLOT + tile * 128 + tid;
    tok_sm[tid] = tok_list[li];     // 0 for padded slots (memset)
    rw_sm[tid] = rw_list[li];       // 0.0f for padded slots
  }
  __syncthreads();

  const int r_in_chunk = lane >> 2;        // 16 rows per 1KB chunk
  const int kpart = (lane & 3) * 8;        // 4 x 8 bf16 per row

  // per-lane gathered A source pointers (waves 0,1 own A chunks 0..7)
  const unsigned short* asrc[4];
  if (w < 2) {
#pragma unroll
    for (int i = 0; i < 4; ++i) {
      int row = (w * 4 + i) * 16 + r_in_chunk;
      asrc[i] = xb + (size_t)tok_sm[row] * H_ + kpart;
    }
  }
  const unsigned short* B1base = w1t + ((size_t)e * I_ + col0) * H_;
  const unsigned short* B3base = w3t + ((size_t)e * I_ + col0) * H_;

  f32x4 acc1[4][2] = {};
  f32x4 acc2[4][2] = {};

  const int lrow = lane & 15;
  const int lk = (lane >> 4) * 8;

  for (int k0 = 0; k0 < H_; k0 += 32) {
    if (w < 2) {
#pragma unroll
      for (int i = 0; i < 4; ++i)
        gload_lds16(asrc[i] + k0, &Asm[(w * 4 + i) * 512]);
    } else if (w == 2) {
#pragma unroll
      for (int i = 0; i < 4; ++i) {
        int row = i * 16 + r_in_chunk;
        gload_lds16(B1base + (size_t)row * H_ + k0 + kpart, &B1sm[i * 512]);
      }
    } else {
#pragma unroll
      for (int i = 0; i < 4; ++i) {
        int row = i * 16 + r_in_chunk;
        gload_lds16(B3base + (size_t)row * H_ + k0 + kpart, &B3sm[i * 512]);
      }
    }
    __syncthreads();  // drains vmcnt before barrier
    bf16x8 af[4], b1f[2], b3f[2];
    for (int m = 0; m < 4; ++m)
      af[m] = *reinterpret_cast<const bf16x8*>(&Asm[(wm * 64 + m * 16 + lrow) * 32 + lk]);
    for (int n = 0; n < 2; ++n) {
      b1f[n] = *reinterpret_cast<const bf16x8*>(&B1sm[(wn * 32 + n * 16 + lrow) * 32 + lk]);
      b3f[n] = *reinterpret_cast<const bf16x8*>(&B3sm[(wn * 32 + n * 16 + lrow) * 32 + lk]);
    }
    for (int m = 0; m < 4; ++m)
      for (int n = 0; n < 2; ++n) {
        acc1[m][n] = __builtin_amdgcn_mfma_f32_16x16x32_bf16(af[m], b1f[n], acc1[m][n], 0, 0, 0);
        acc2[m][n] = __builtin_amdgcn_mfma_f32_16x16x32_bf16(af[m], b3f[n], acc2[m][n], 0, 0, 0);
      }
    __syncthreads();
  }

  // epilogue: C row = (lane>>4)*4 + reg, col = lane&15
  const int crow = (lane >> 4) * 4;
  const int ccol = lane & 15;
  for (int m = 0; m < 4; ++m)
    for (int n = 0; n < 2; ++n)
      for (int r = 0; r < 4; ++r) {
        int rl = wm * 64 + m * 16 + crow + r;
        int cl = wn * 32 + n * 16 + ccol;
        float hv = acc1[m][n][r];
        float uv = acc2[m][n][r];
        float a = (hv / (1.f + __expf(-hv))) * uv * rw_sm[rl];
        act_g[(size_t)(slot0 + rl) * I_ + col0 + cl] = f2bf(a);
      }
}

// ---------------- Sparse down GEMM: scatter-add into out --------------------
// Per expert e: [128 slots, I] @ [I, 128 h-cols], K=I=768, atomicAdd epilogue.
__global__ __launch_bounds__(256) void moe_down_kernel(
    const unsigned short* __restrict__ act_g, // [ACT_ROWS][I] bf16
    const unsigned short* __restrict__ w2te,  // [E][H][I] bf16 (B^T per expert)
    const int* __restrict__ tok_list,         // [E][MAXSLOT]
    const int* __restrict__ off,
    const int* __restrict__ ntiles,
    float* __restrict__ out) {                // [T][H] f32 (pre-zeroed)
  const int e = blockIdx.z;
  const int tile = blockIdx.x;
  if (tile >= ntiles[e]) return;

  __shared__ __align__(16) unsigned short Asm[128 * 32];
  __shared__ __align__(16) unsigned short Bsm[128 * 32];
  __shared__ int tok_sm[128];

  const int col0 = blockIdx.y * 128;
  const int tid = threadIdx.x;
  const int lane = tid & 63;
  const int w = tid >> 6;
  const int wm = w >> 1, wn = w & 1;

  if (tid < 128) tok_sm[tid] = tok_list[e * MAXSLOT + tile * 128 + tid];

  const int r_in_chunk = lane >> 2;
  const int kpart = (lane & 3) * 8;

  const unsigned short* Abase = act_g + (size_t)(off[e] + tile * 128) * I_;
  const unsigned short* Bbase = w2te + ((size_t)e * H_ + col0) * I_;

  f32x4 acc[4][4] = {};

  const int lrow = lane & 15;
  const int lk = (lane >> 4) * 8;

  for (int k0 = 0; k0 < I_; k0 += 32) {
    for (int i = 0; i < 2; ++i) {
      int c = w * 2 + i;
      int row = c * 16 + r_in_chunk;
      gload_lds16(Abase + (size_t)row * I_ + k0 + kpart, &Asm[c * 512]);
      gload_lds16(Bbase + (size_t)row * I_ + k0 + kpart, &Bsm[c * 512]);
    }
    __syncthreads();
    bf16x8 af[4], bf[4];
    for (int m = 0; m < 4; ++m)
      af[m] = *reinterpret_cast<const bf16x8*>(&Asm[(wm * 64 + m * 16 + lrow) * 32 + lk]);
    for (int n = 0; n < 4; ++n)
      bf[n] = *reinterpret_cast<const bf16x8*>(&Bsm[(wn * 64 + n * 16 + lrow) * 32 + lk]);
    for (int m = 0; m < 4; ++m)
      for (int n = 0; n < 4; ++n)
        acc[m][n] = __builtin_amdgcn_mfma_f32_16x16x32_bf16(af[m], bf[n], acc[m][n], 0, 0, 0);
    __syncthreads();
  }

  const int crow = (lane >> 4) * 4;
  const int ccol = lane & 15;
  for (int m = 0; m < 4; ++m)
    for (int n = 0; n < 4; ++n)
      for (int r = 0; r < 4; ++r) {
        int rl = wm * 64 + m * 16 + crow + r;
        int cl = wn * 64 + n * 16 + ccol;
        atomicAdd(&out[(size_t)tok_sm[rl] * H_ + col0 + cl], acc[m][n][r]);
      }
}

extern "C" void kernel_launch(void* const* d_in, const int* in_sizes, int n_in,
                              void* d_out, int out_size, void* d_ws, size_t ws_size,
                              hipStream_t stream) {
  const float* x      = (const float*)d_in[0];
  const float* gate_w = (const float*)d_in[1];
  const float* w1     = (const float*)d_in[2];
  const float* w3     = (const float*)d_in[3];
  const float* w2     = (const float*)d_in[4];
  float* out = (float*)d_out;

  // workspace layout: ctrl block + lists + bf16 buffers (~132 MB total)
  int* ctrl     = (int*)d_ws;                // cnt[16], off[16], ntiles[16], pad
  int* cnt      = ctrl;
  int* off      = ctrl + 16;
  int* ntiles   = ctrl + 32;
  int* tok_list = ctrl + 64;                          // 16*4096 ints = 256KB
  float* rw_list = (float*)(tok_list + E_ * MAXSLOT); // 256KB
  unsigned short* xb   = (unsigned short*)(rw_list + E_ * MAXSLOT); // 8MB
  unsigned short* w1t  = xb  + (size_t)T_ * H_;        // 24MB
  unsigned short* w3t  = w1t + (size_t)E_ * I_ * H_;   // 24MB
  unsigned short* w2te = w3t + (size_t)E_ * I_ * H_;   // 24MB
  unsigned short* act_g = w2te + (size_t)E_ * H_ * I_; // ACT_ROWS*I*2 = 51MB

  // zero ctrl+lists (padded slots -> tok 0, rw 0.0) and the output accumulator
  hipMemsetAsync(d_ws, 0, (64 + 2 * E_ * MAXSLOT) * sizeof(int), stream);
  hipMemsetAsync(d_out, 0, (size_t)T_ * H_ * sizeof(float), stream);

  router_kernel<<<T_, 64, 0, stream>>>(x, gate_w, cnt, tok_list, rw_list);
  offsets_kernel<<<1, 1, 0, stream>>>(cnt, off, ntiles);
  cast_x_kernel<<<(T_ * H_ / 4) / 256, 256, 0, stream>>>(x, xb);
  transpose_w13_kernel<<<dim3(I_ / 64, H_ / 64, 32), 256, 0, stream>>>(w1, w3, w1t, w3t);
  transpose_w2_kernel<<<dim3(H_ / 64, I_ / 64, E_), 256, 0, stream>>>(w2, w2te);
  moe_up_kernel<<<dim3(32, I_ / 64, E_), 256, 0, stream>>>(
      xb, w1t, w3t, tok_list, rw_list, off, ntiles, act_g);
  moe_down_kernel<<<dim3(32, H_ / 128, E_), 256, 0, stream>>>(
      act_g, w2te, tok_list, off, ntiles, out);
}

// Round 4
// 620.521 us; speedup vs baseline: 1.2477x; 1.2477x over previous
//
#include <hip/hip_runtime.h>
#include <hip/hip_bf16.h>

// Problem constants
#define T_ 4096
#define H_ 1024
#define E_ 16
#define I_ 768
#define KTOP 8
#define MAXSLOT 4096      // per-expert token list capacity (hard upper bound)
#define ACT_ROWS 34816    // >= 32768 + 16*127 (per-expert pad to 128)

typedef __attribute__((ext_vector_type(8))) short bf16x8;
typedef __attribute__((ext_vector_type(4))) float f32x4;

__device__ __forceinline__ unsigned short f2bf(float f) {
  unsigned u = __builtin_bit_cast(unsigned, f);
  u += 0x7fff + ((u >> 16) & 1);   // round-to-nearest-even
  return (unsigned short)(u >> 16);
}
__device__ __forceinline__ float bf2f(unsigned short u) {
  unsigned v = ((unsigned)u) << 16;
  return __builtin_bit_cast(float, v);
}

typedef __attribute__((address_space(3))) void lds_void;
typedef __attribute__((address_space(1))) void g_void;

__device__ __forceinline__ void gload_lds16(const void* g, void* l) {
  __builtin_amdgcn_global_load_lds((g_void*)g, (lds_void*)l, 16, 0, 0);
}

// ---------------- Router: logits -> softmax -> top8 -> append to lists ------
// one wave per token; e = lane&15, chunk = lane>>4 (4 H-chunks of 256)
__global__ void router_kernel(const float* __restrict__ x,
                              const float* __restrict__ gate_w,
                              int* __restrict__ cnt,
                              int* __restrict__ tok_list,
                              float* __restrict__ rw_list,
                              int* __restrict__ tok2es) {
  int t = blockIdx.x;
  int lane = threadIdx.x;
  int e = lane & 15;
  int chunk = lane >> 4;
  const float* xr = x + (size_t)t * H_;
  int h0 = chunk * 256;
  float partial = 0.f;
  for (int i = 0; i < 256; i += 4) {
    float4 xv = *reinterpret_cast<const float4*>(xr + h0 + i);
    partial += xv.x * gate_w[(size_t)(h0 + i    ) * E_ + e];
    partial += xv.y * gate_w[(size_t)(h0 + i + 1) * E_ + e];
    partial += xv.z * gate_w[(size_t)(h0 + i + 2) * E_ + e];
    partial += xv.w * gate_w[(size_t)(h0 + i + 3) * E_ + e];
  }
  partial += __shfl_xor(partial, 16);
  partial += __shfl_xor(partial, 32);
  float logit = partial;
  float m = logit;
  for (int d = 1; d < 16; d <<= 1) m = fmaxf(m, __shfl_xor(m, d));
  float p = __expf(logit - m);
  int base = lane & ~15;
  int rank = 0;
  for (int j = 0; j < 16; ++j) {
    float pj = __shfl(p, base + j);
    rank += (pj > p) || (pj == p && j < e);
  }
  bool sel = rank < KTOP;
  float contrib = sel ? p : 0.f;
  float s = contrib;
  for (int d = 1; d < 16; d <<= 1) s += __shfl_xor(s, d);
  float w = sel ? p / s : 0.f;
  if (lane < 16 && sel) {
    int slot = atomicAdd(&cnt[e], 1);
    tok_list[e * MAXSLOT + slot] = t;
    rw_list[e * MAXSLOT + slot] = w;
    tok2es[t * KTOP + rank] = (e << 20) | slot;   // token's k-th expert
  }
}

// ---------------- Offsets: per-expert padded prefix sum (1 thread) ----------
__global__ void offsets_kernel(const int* __restrict__ cnt,
                               int* __restrict__ off,
                               int* __restrict__ ntiles) {
  int acc = 0;
  for (int e = 0; e < E_; ++e) {
    off[e] = acc;
    int nt = (cnt[e] + 127) >> 7;
    ntiles[e] = nt;
    acc += nt << 7;
  }
}

// ---------------- Cast x (f32 -> bf16), 4 elems/thread ----------------
__global__ void cast_x_kernel(const float* __restrict__ x,
                              unsigned short* __restrict__ xb) {
  int idx = blockIdx.x * blockDim.x + threadIdx.x;
  float4 v = reinterpret_cast<const float4*>(x)[idx];
  ushort4 o;
  o.x = f2bf(v.x); o.y = f2bf(v.y); o.z = f2bf(v.z); o.w = f2bf(v.w);
  *reinterpret_cast<ushort4*>(xb + (size_t)idx * 4) = o;
}

// ---------------- Transpose+cast w1/w3: [E][H][I] f32 -> [E][I][H] bf16 -----
__global__ void transpose_w13_kernel(const float* __restrict__ w1,
                                     const float* __restrict__ w3,
                                     unsigned short* __restrict__ w1t,
                                     unsigned short* __restrict__ w3t) {
  __shared__ float tile[64][65];
  int i0 = blockIdx.x * 64;
  int h0 = blockIdx.y * 64;
  int e = blockIdx.z & 15;
  const float* src = (blockIdx.z < 16 ? w1 : w3) + (size_t)e * H_ * I_;
  unsigned short* dst = (blockIdx.z < 16 ? w1t : w3t) + (size_t)e * I_ * H_;
  int tx = threadIdx.x & 63, ty = threadIdx.x >> 6;
  for (int r = 0; r < 64; r += 4)
    tile[ty + r][tx] = src[(size_t)(h0 + ty + r) * I_ + i0 + tx];
  __syncthreads();
  for (int r = 0; r < 64; r += 4) {
    int i = ty + r;
    dst[(size_t)(i0 + i) * H_ + h0 + tx] = f2bf(tile[tx][i]);
  }
}

// ---------------- Transpose+cast w2: [E][I][H] f32 -> [E][H][I] bf16 --------
__global__ void transpose_w2_kernel(const float* __restrict__ w2,
                                    unsigned short* __restrict__ w2te) {
  __shared__ float tile[64][65];
  int h0 = blockIdx.x * 64;
  int i0 = blockIdx.y * 64;
  int e = blockIdx.z;
  const float* src = w2 + (size_t)e * I_ * H_;
  int tx = threadIdx.x & 63, ty = threadIdx.x >> 6;
  for (int r = 0; r < 64; r += 4)
    tile[ty + r][tx] = src[(size_t)(i0 + ty + r) * H_ + h0 + tx];
  __syncthreads();
  for (int r = 0; r < 64; r += 4) {
    int h = ty + r;
    w2te[((size_t)e * H_ + h0 + h) * I_ + i0 + tx] = f2bf(tile[tx][h]);
  }
}

// ---------------- Gathered up/gate GEMM + SwiGLU + route-scale --------------
// Per expert e, row-tile = 128 gathered token slots; 128x64 tile, BK=32,
// 4 waves: w0,w1 stage A (gathered); w2 stages B1; w3 stages B3.
__global__ __launch_bounds__(256) void moe_up_kernel(
    const unsigned short* __restrict__ xb,    // [T][H] bf16
    const unsigned short* __restrict__ w1t,   // [E][I][H] bf16
    const unsigned short* __restrict__ w3t,   // [E][I][H] bf16
    const int* __restrict__ tok_list,         // [E][MAXSLOT]
    const float* __restrict__ rw_list,        // [E][MAXSLOT]
    const int* __restrict__ off,              // [E]
    const int* __restrict__ ntiles,           // [E]
    unsigned short* __restrict__ act_g) {     // [ACT_ROWS][I] bf16
  const int e = blockIdx.z;
  const int tile = blockIdx.x;
  if (tile >= ntiles[e]) return;

  __shared__ __align__(16) unsigned short Asm[128 * 32];   // 8KB
  __shared__ __align__(16) unsigned short B1sm[64 * 32];   // 4KB
  __shared__ __align__(16) unsigned short B3sm[64 * 32];   // 4KB
  __shared__ int tok_sm[128];
  __shared__ float rw_sm[128];

  const int col0 = blockIdx.y * 64;
  const int tid = threadIdx.x;
  const int lane = tid & 63;
  const int w = tid >> 6;
  const int wm = w >> 1, wn = w & 1;
  const int slot0 = off[e] + tile * 128;

  if (tid < 128) {
    int li = e * MAXSLOT + tile * 128 + tid;
    tok_sm[tid] = tok_list[li];     // 0 for padded slots (memset)
    rw_sm[tid] = rw_list[li];       // 0.0f for padded slots
  }
  __syncthreads();

  const int r_in_chunk = lane >> 2;        // 16 rows per 1KB chunk
  const int kpart = (lane & 3) * 8;        // 4 x 8 bf16 per row

  // per-lane gathered A source pointers (waves 0,1 own A chunks 0..7)
  const unsigned short* asrc[4];
  if (w < 2) {
#pragma unroll
    for (int i = 0; i < 4; ++i) {
      int row = (w * 4 + i) * 16 + r_in_chunk;
      asrc[i] = xb + (size_t)tok_sm[row] * H_ + kpart;
    }
  }
  const unsigned short* B1base = w1t + ((size_t)e * I_ + col0) * H_;
  const unsigned short* B3base = w3t + ((size_t)e * I_ + col0) * H_;

  f32x4 acc1[4][2] = {};
  f32x4 acc2[4][2] = {};

  const int lrow = lane & 15;
  const int lk = (lane >> 4) * 8;

  for (int k0 = 0; k0 < H_; k0 += 32) {
    if (w < 2) {
#pragma unroll
      for (int i = 0; i < 4; ++i)
        gload_lds16(asrc[i] + k0, &Asm[(w * 4 + i) * 512]);
    } else if (w == 2) {
#pragma unroll
      for (int i = 0; i < 4; ++i) {
        int row = i * 16 + r_in_chunk;
        gload_lds16(B1base + (size_t)row * H_ + k0 + kpart, &B1sm[i * 512]);
      }
    } else {
#pragma unroll
      for (int i = 0; i < 4; ++i) {
        int row = i * 16 + r_in_chunk;
        gload_lds16(B3base + (size_t)row * H_ + k0 + kpart, &B3sm[i * 512]);
      }
    }
    __syncthreads();  // drains vmcnt before barrier
    bf16x8 af[4], b1f[2], b3f[2];
    for (int m = 0; m < 4; ++m)
      af[m] = *reinterpret_cast<const bf16x8*>(&Asm[(wm * 64 + m * 16 + lrow) * 32 + lk]);
    for (int n = 0; n < 2; ++n) {
      b1f[n] = *reinterpret_cast<const bf16x8*>(&B1sm[(wn * 32 + n * 16 + lrow) * 32 + lk]);
      b3f[n] = *reinterpret_cast<const bf16x8*>(&B3sm[(wn * 32 + n * 16 + lrow) * 32 + lk]);
    }
    for (int m = 0; m < 4; ++m)
      for (int n = 0; n < 2; ++n) {
        acc1[m][n] = __builtin_amdgcn_mfma_f32_16x16x32_bf16(af[m], b1f[n], acc1[m][n], 0, 0, 0);
        acc2[m][n] = __builtin_amdgcn_mfma_f32_16x16x32_bf16(af[m], b3f[n], acc2[m][n], 0, 0, 0);
      }
    __syncthreads();
  }

  // epilogue: C row = (lane>>4)*4 + reg, col = lane&15
  const int crow = (lane >> 4) * 4;
  const int ccol = lane & 15;
  for (int m = 0; m < 4; ++m)
    for (int n = 0; n < 2; ++n)
      for (int r = 0; r < 4; ++r) {
        int rl = wm * 64 + m * 16 + crow + r;
        int cl = wn * 32 + n * 16 + ccol;
        float hv = acc1[m][n][r];
        float uv = acc2[m][n][r];
        float a = (hv / (1.f + __expf(-hv))) * uv * rw_sm[rl];
        act_g[(size_t)(slot0 + rl) * I_ + col0 + cl] = f2bf(a);
      }
}

// ---------------- Sparse down GEMM: plain bf16 stores to dout_g -------------
// Per expert e: [128 slots, I] @ [I, 128 h-cols], K=I=768.
__global__ __launch_bounds__(256) void moe_down_kernel(
    const unsigned short* __restrict__ act_g, // [ACT_ROWS][I] bf16
    const unsigned short* __restrict__ w2te,  // [E][H][I] bf16 (B^T per expert)
    const int* __restrict__ off,
    const int* __restrict__ ntiles,
    unsigned short* __restrict__ dout_g) {    // [ACT_ROWS][H] bf16
  const int e = blockIdx.z;
  const int tile = blockIdx.x;
  if (tile >= ntiles[e]) return;

  __shared__ __align__(16) unsigned short Asm[128 * 32];
  __shared__ __align__(16) unsigned short Bsm[128 * 32];

  const int col0 = blockIdx.y * 128;
  const int tid = threadIdx.x;
  const int lane = tid & 63;
  const int w = tid >> 6;
  const int wm = w >> 1, wn = w & 1;
  const int slot0 = off[e] + tile * 128;

  const int r_in_chunk = lane >> 2;
  const int kpart = (lane & 3) * 8;

  const unsigned short* Abase = act_g + (size_t)slot0 * I_;
  const unsigned short* Bbase = w2te + ((size_t)e * H_ + col0) * I_;

  f32x4 acc[4][4] = {};

  const int lrow = lane & 15;
  const int lk = (lane >> 4) * 8;

  for (int k0 = 0; k0 < I_; k0 += 32) {
    for (int i = 0; i < 2; ++i) {
      int c = w * 2 + i;
      int row = c * 16 + r_in_chunk;
      gload_lds16(Abase + (size_t)row * I_ + k0 + kpart, &Asm[c * 512]);
      gload_lds16(Bbase + (size_t)row * I_ + k0 + kpart, &Bsm[c * 512]);
    }
    __syncthreads();
    bf16x8 af[4], bf[4];
    for (int m = 0; m < 4; ++m)
      af[m] = *reinterpret_cast<const bf16x8*>(&Asm[(wm * 64 + m * 16 + lrow) * 32 + lk]);
    for (int n = 0; n < 4; ++n)
      bf[n] = *reinterpret_cast<const bf16x8*>(&Bsm[(wn * 64 + n * 16 + lrow) * 32 + lk]);
    for (int m = 0; m < 4; ++m)
      for (int n = 0; n < 4; ++n)
        acc[m][n] = __builtin_amdgcn_mfma_f32_16x16x32_bf16(af[m], bf[n], acc[m][n], 0, 0, 0);
    __syncthreads();
  }

  const int crow = (lane >> 4) * 4;
  const int ccol = lane & 15;
  for (int m = 0; m < 4; ++m)
    for (int n = 0; n < 4; ++n)
      for (int r = 0; r < 4; ++r) {
        int rl = wm * 64 + m * 16 + crow + r;
        int cl = wn * 64 + n * 16 + ccol;
        dout_g[(size_t)(slot0 + rl) * H_ + col0 + cl] = f2bf(acc[m][n][r]);
      }
}

// ---------------- Combine: out[t] = sum_k dout_g[gslot(t,k)] ----------------
__global__ __launch_bounds__(256) void combine_kernel(
    const unsigned short* __restrict__ dout_g, // [ACT_ROWS][H] bf16
    const int* __restrict__ tok2es,            // [T][KTOP] packed (e<<20)|slot
    const int* __restrict__ off,               // [E]
    float* __restrict__ out) {                 // [T][H] f32
  __shared__ int gs[KTOP];
  int t = blockIdx.x;
  if (threadIdx.x < KTOP) {
    int es = tok2es[t * KTOP + threadIdx.x];
    int e = es >> 20, s = es & 0xFFFFF;
    gs[threadIdx.x] = off[e] + s;
  }
  __syncthreads();
  int h = threadIdx.x * 4;
  float4 sum = {0.f, 0.f, 0.f, 0.f};
#pragma unroll
  for (int k = 0; k < KTOP; ++k) {
    ushort4 v = *reinterpret_cast<const ushort4*>(&dout_g[(size_t)gs[k] * H_ + h]);
    sum.x += bf2f(v.x);
    sum.y += bf2f(v.y);
    sum.z += bf2f(v.z);
    sum.w += bf2f(v.w);
  }
  *reinterpret_cast<float4*>(&out[(size_t)t * H_ + h]) = sum;
}

extern "C" void kernel_launch(void* const* d_in, const int* in_sizes, int n_in,
                              void* d_out, int out_size, void* d_ws, size_t ws_size,
                              hipStream_t stream) {
  const float* x      = (const float*)d_in[0];
  const float* gate_w = (const float*)d_in[1];
  const float* w1     = (const float*)d_in[2];
  const float* w3     = (const float*)d_in[3];
  const float* w2     = (const float*)d_in[4];
  float* out = (float*)d_out;

  // workspace layout (peak ~152 MB, within the 176 MB proven in R1):
  //   [0,1MB)    ctrl + tok_list + rw_list + tok2es
  //   [1,9)      xb 8MB
  //   [9,33)     w2te 24MB
  //   [33,84)    act_g 51MB
  //   [84,108)   w1t 24MB   <- dead after moe_up
  //   [108,132)  w3t 24MB   <- dead after moe_up
  //   [84,152)   dout_g 68MB (aliases w1t+w3t)
  char* ws = (char*)d_ws;
  int* ctrl     = (int*)ws;                   // cnt[16], off[16], ntiles[16]
  int* cnt      = ctrl;
  int* off      = ctrl + 16;
  int* ntiles   = ctrl + 32;
  int* tok_list = ctrl + 64;                          // 16*4096 ints = 256KB
  float* rw_list = (float*)(tok_list + E_ * MAXSLOT); // 256KB
  int* tok2es   = (int*)(rw_list + E_ * MAXSLOT);     // 4096*8 ints = 128KB
  unsigned short* xb    = (unsigned short*)(ws + (1 << 20));          // 8MB
  unsigned short* w2te  = xb + (size_t)T_ * H_;                       // 24MB
  unsigned short* act_g = w2te + (size_t)E_ * H_ * I_;                // 51MB
  unsigned short* w1t   = act_g + (size_t)ACT_ROWS * I_;              // 24MB
  unsigned short* w3t   = w1t + (size_t)E_ * I_ * H_;                 // 24MB
  unsigned short* dout_g = w1t;   // aliases w1t+w3t (dead after moe_up), 68MB

  // zero ctrl+lists (padded slots -> tok 0, rw 0.0)
  hipMemsetAsync(d_ws, 0, (64 + 2 * E_ * MAXSLOT + T_ * KTOP) * sizeof(int), stream);

  router_kernel<<<T_, 64, 0, stream>>>(x, gate_w, cnt, tok_list, rw_list, tok2es);
  offsets_kernel<<<1, 1, 0, stream>>>(cnt, off, ntiles);
  cast_x_kernel<<<(T_ * H_ / 4) / 256, 256, 0, stream>>>(x, xb);
  transpose_w13_kernel<<<dim3(I_ / 64, H_ / 64, 32), 256, 0, stream>>>(w1, w3, w1t, w3t);
  transpose_w2_kernel<<<dim3(H_ / 64, I_ / 64, E_), 256, 0, stream>>>(w2, w2te);
  moe_up_kernel<<<dim3(32, I_ / 64, E_), 256, 0, stream>>>(
      xb, w1t, w3t, tok_list, rw_list, off, ntiles, act_g);
  moe_down_kernel<<<dim3(32, H_ / 128, E_), 256, 0, stream>>>(
      act_g, w2te, off, ntiles, dout_g);
  combine_kernel<<<T_, 256, 0, stream>>>(dout_g, tok2es, off, out);
}